// Round 1
// 161.276 us; speedup vs baseline: 1.0786x; 1.0786x over previous
//
#include <hip/hip_runtime.h>
#include <hip/hip_bf16.h>

// CfC / liquid-RNN scan on MFMA, R7: wave-autonomous, ZERO barriers, ZERO LDS.
// R6 post-mortem: 6750 cyc/step/CU vs ~700 cyc of issued work -> barrier/
// latency-bound, not pipe-bound. R7: one wave owns 16 pixels and the whole
// net. Weight-row/col permutations (applied at load) make phase1-C -> phase2-B
// and phase2-C(h) -> phase1-B(z) LANE-LOCAL register repacks:
//   phase2 A cols: n = 32*kt + (j>>2)*16 + lq*4 + (j&3)
//   head rows:     lane lq gates units ((lq+2)&3)*8 + i  (head = r in acc regs)
// so h lands exactly in this lane's own z-frag slots (kt=1-(lq>=2), j=i).
// Numerics identical to R6 (weights hi+lo bf16 split, activations/x/h bf16 RNE
// via v_cvt_pk_bf16_f32) -> expected absmax ~0.0098. 1024 one-wave blocks
// -> 1 wave/SIMD; all latency hidden by ILP (4-8 indep MFMA chains, x prefetch).

#define CIN      16
#define UNITS    32
#define BACKBONE 64
#define CZ       48
#define TSTEPS   32
#define HW       4096
#define NPIX     16
#define NTHREADS 64

typedef __attribute__((ext_vector_type(8))) short  short8;
typedef __attribute__((ext_vector_type(8))) __bf16 bf16x8;
typedef __attribute__((ext_vector_type(4))) float  float4v;
typedef __attribute__((ext_vector_type(4))) unsigned int uint4v;

__device__ __forceinline__ unsigned short bf16_rne(float f) {
    unsigned u = __float_as_uint(f);
    return (unsigned short)((u + 0x7FFFu + ((u >> 16) & 1u)) >> 16);
}
__device__ __forceinline__ float bf16_tof(unsigned short h) {
    return __uint_as_float(((unsigned)h) << 16);
}
// packed f32x2 -> bf16x2 (RNE), single VALU op
__device__ __forceinline__ unsigned cvt_pk_bf16(float lo, float hi) {
    unsigned r;
    asm("v_cvt_pk_bf16_f32 %0, %1, %2" : "=v"(r) : "v"(lo), "v"(hi));
    return r;
}

#if __has_builtin(__builtin_amdgcn_exp2f)
#define EXP2F(x) __builtin_amdgcn_exp2f(x)
#else
#define EXP2F(x) __expf(0.69314718056f * (x))
#endif
#if __has_builtin(__builtin_amdgcn_rcpf)
#define RCPF(x) __builtin_amdgcn_rcpf(x)
#else
#define RCPF(x) __fdividef(1.0f, (x))
#endif

// 1.7159*tanh(0.666*v) = 1.7159 - 3.4318/(2^(1.332*log2e*v)+1)  [5 VALU ops]
__device__ __forceinline__ float lecun_tanh_f(float v) {
    float e = EXP2F(1.92166925f * v);
    return fmaf(-3.4318f, RCPF(e + 1.0f), 1.7159f);
}
__device__ __forceinline__ float tanh_f(float v) {
    float e = EXP2F(2.88539008f * v);
    return fmaf(-2.0f, RCPF(e + 1.0f), 1.0f);
}
__device__ __forceinline__ float sigmoid_f(float v) {
    float e = EXP2F(-1.44269504f * v);
    return RCPF(1.0f + e);
}
__device__ __forceinline__ float4v mfma16(bf16x8 a, bf16x8 b, float4v c) {
    return __builtin_amdgcn_mfma_f32_16x16x32_bf16(a, b, c, 0, 0, 0);
}
__device__ __forceinline__ void split8(const float* v, bf16x8& hi, bf16x8& lo) {
    short8 sh, sl;
    #pragma unroll
    for (int j = 0; j < 8; ++j) {
        unsigned short h = bf16_rne(v[j]);
        sh[j] = (short)h;
        sl[j] = (short)bf16_rne(v[j] - bf16_tof(h));
    }
    hi = __builtin_bit_cast(bf16x8, sh);
    lo = __builtin_bit_cast(bf16x8, sl);
}

__global__ __launch_bounds__(NTHREADS, 1)
void cfc_mfma_kernel(const float* __restrict__ x,   const float* __restrict__ Wb,
                     const float* __restrict__ bb,
                     const float* __restrict__ Wff1, const float* __restrict__ bff1,
                     const float* __restrict__ Wff2, const float* __restrict__ bff2,
                     const float* __restrict__ Wta,  const float* __restrict__ bta,
                     const float* __restrict__ Wtb,  const float* __restrict__ btb,
                     float* __restrict__ out)
{
    const int lane = threadIdx.x;       // one wave per block
    const int ln   = lane & 15;         // MFMA m/n (pixel for B/C)
    const int lq   = lane >> 4;         // MFMA quad

    const int gpix = blockIdx.x * NPIX;
    const int b    = gpix >> 12;
    const int pinb = gpix & 4095;
    const int px   = pinb + ln;

    // ---- phase-1 A frags: backbone weights, identity rows, hi+lo ----------
    // tile mt: rows mt*16+ln, cols c = kt*32 + lq*8 + j (c>=CZ zero-padded)
    bf16x8 Abb_hi[4][2], Abb_lo[4][2];
    #pragma unroll
    for (int mt = 0; mt < 4; ++mt) {
        #pragma unroll
        for (int kt = 0; kt < 2; ++kt) {
            float v[8];
            #pragma unroll
            for (int j = 0; j < 8; ++j) {
                int c = kt * 32 + lq * 8 + j;
                v[j] = (c < CZ) ? Wb[(mt * 16 + ln) * CZ + c] : 0.0f;
            }
            split8(v, Abb_hi[mt][kt], Abb_lo[mt][kt]);
        }
    }
    float bbias[4][4];
    #pragma unroll
    for (int mt = 0; mt < 4; ++mt)
        #pragma unroll
        for (int r = 0; r < 4; ++r)
            bbias[mt][r] = bb[mt * 16 + lq * 4 + r];

    // ---- phase-2 A frags: head weights, permuted rows & cols, hi+lo -------
    // row m=ln of tile i -> unit (((ln>>2)+2)&3)*8 + i, head ln&3
    // col k (=(lq)*8+j within kt) -> backbone neuron n = 32kt+(j>>2)*16+lq*4+(j&3)
    const int head = ln & 3;
    const float* Whp = (head == 0) ? Wff1 : (head == 1) ? Wff2 : (head == 2) ? Wta : Wtb;
    const int urow = (((ln >> 2) + 2) & 3) * 8;
    bf16x8 Ah_hi[8][2], Ah_lo[8][2];
    #pragma unroll
    for (int i = 0; i < 8; ++i) {
        #pragma unroll
        for (int kt = 0; kt < 2; ++kt) {
            float v[8];
            #pragma unroll
            for (int j = 0; j < 8; ++j) {
                int n = 32 * kt + (j >> 2) * 16 + lq * 4 + (j & 3);
                v[j] = Whp[(urow + i) * BACKBONE + n];
            }
            split8(v, Ah_hi[i][kt], Ah_lo[i][kt]);
        }
    }
    // gate-side units of THIS lane (C-layout rows lq*4+r -> unit ub+i, head r)
    const int ub = ((lq + 2) & 3) * 8;
    float hbias[8][4];
    #pragma unroll
    for (int i = 0; i < 8; ++i) {
        int u = ub + i;
        hbias[i][0] = bff1[u]; hbias[i][1] = bff2[u];
        hbias[i][2] = bta[u];  hbias[i][3] = btb[u];
    }

    // ---- per-lane global offsets (32-bit, saddr-friendly) ------------------
    const int cb = (lq & 1) * 8;        // lq2,3 mirror lq0,1 (L1-absorbed dup)
    unsigned xo[8], oo[8];
    #pragma unroll
    for (int j = 0; j < 8; ++j)
        xo[j] = (unsigned)(((b * CIN + cb + j) * TSTEPS) * HW + px);
    #pragma unroll
    for (int i = 0; i < 8; ++i)
        oo[i] = (unsigned)(((b * UNITS + ub + i) * TSTEPS) * HW + px);

    // ---- prologue: x_0 prefetch, h=0 --------------------------------------
    float xa[8], xb2[8];
    #pragma unroll
    for (int j = 0; j < 8; ++j) xa[j] = x[xo[j]];
    unsigned hpk[4] = {0u, 0u, 0u, 0u};   // h bf16-packed, frag slots j=i
    unsigned toff = 0;

    auto step = [&](int t, float (&xc)[8], float (&xn)[8]) {
        // prefetch x_{t+1} (dummy re-read at t=31)
        const unsigned tn = toff + ((t < TSTEPS - 1) ? (unsigned)HW : 0u);
        #pragma unroll
        for (int j = 0; j < 8; ++j) xn[j] = x[xo[j] + tn];

        // ---- build z fragments (pure in-register) ----
        unsigned xpk[4];
        #pragma unroll
        for (int p = 0; p < 4; ++p) xpk[p] = cvt_pk_bf16(xc[2 * p], xc[2 * p + 1]);
        const bool xl = (lq < 2);       // this lane's kt0 slots carry x
        unsigned z0u[4], z1u[4];
        #pragma unroll
        for (int p = 0; p < 4; ++p) {
            z0u[p] = xl ? xpk[p] : hpk[p];
            z1u[p] = xl ? hpk[p] : 0u;  // lq2,3 kt1 = K-pad zeros
        }
        uint4v zv0 = {z0u[0], z0u[1], z0u[2], z0u[3]};
        uint4v zv1 = {z1u[0], z1u[1], z1u[2], z1u[3]};
        bf16x8 Z0 = __builtin_bit_cast(bf16x8, zv0);
        bf16x8 Z1 = __builtin_bit_cast(bf16x8, zv1);

        // ---- phase 1: backbone, 4 indep chains x 4 MFMA ----
        float4v acc[4];
        #pragma unroll
        for (int mt = 0; mt < 4; ++mt) {
            float4v a = {bbias[mt][0], bbias[mt][1], bbias[mt][2], bbias[mt][3]};
            a = mfma16(Abb_hi[mt][0], Z0, a);
            a = mfma16(Abb_lo[mt][0], Z0, a);
            a = mfma16(Abb_hi[mt][1], Z1, a);
            a = mfma16(Abb_lo[mt][1], Z1, a);
            acc[mt] = a;
        }

        // ---- lecun_tanh + lane-local repack C -> phase-2 B frags ----
        // slot j of frag kt <- acc[2kt + (j>>2)][j&3]
        bf16x8 A2[2];
        #pragma unroll
        for (int kt = 0; kt < 2; ++kt) {
            unsigned w[4];
            #pragma unroll
            for (int h2 = 0; h2 < 2; ++h2) {
                float g0 = lecun_tanh_f(acc[2 * kt + h2][0]);
                float g1 = lecun_tanh_f(acc[2 * kt + h2][1]);
                float g2 = lecun_tanh_f(acc[2 * kt + h2][2]);
                float g3 = lecun_tanh_f(acc[2 * kt + h2][3]);
                w[2 * h2 + 0] = cvt_pk_bf16(g0, g1);
                w[2 * h2 + 1] = cvt_pk_bf16(g2, g3);
            }
            uint4v wv = {w[0], w[1], w[2], w[3]};
            A2[kt] = __builtin_bit_cast(bf16x8, wv);
        }

        // ---- phase 2: 8 tiles x 4 MFMA, in-register gate, store, h pack ----
        float hn[8];
        #pragma unroll
        for (int i = 0; i < 8; ++i) {
            float4v c = {hbias[i][0], hbias[i][1], hbias[i][2], hbias[i][3]};
            c = mfma16(Ah_hi[i][0], A2[0], c);
            c = mfma16(Ah_lo[i][0], A2[0], c);
            c = mfma16(Ah_hi[i][1], A2[1], c);
            c = mfma16(Ah_lo[i][1], A2[1], c);
            float f1 = tanh_f(c[0]);
            float f2 = tanh_f(c[1]);
            float ti = sigmoid_f(c[2] + c[3]);
            float h  = fmaf(ti, f2 - f1, f1);
            out[oo[i] + toff] = h;
            hn[i] = h;
        }
        #pragma unroll
        for (int p = 0; p < 4; ++p) hpk[p] = cvt_pk_bf16(hn[2 * p], hn[2 * p + 1]);
        toff += (unsigned)HW;
    };

    #pragma unroll 1
    for (int t = 0; t < TSTEPS; t += 2) {
        step(t,     xa,  xb2);   // ping
        step(t + 1, xb2, xa);    // pong (static x double-buffer, rule #20)
    }
}

extern "C" void kernel_launch(void* const* d_in, const int* in_sizes, int n_in,
                              void* d_out, int out_size, void* d_ws, size_t ws_size,
                              hipStream_t stream) {
    dim3 grid(4 * HW / NPIX);   // 1024 one-wave blocks -> 1 wave/SIMD
    cfc_mfma_kernel<<<grid, NTHREADS, 0, stream>>>(
        (const float*)d_in[0], (const float*)d_in[1], (const float*)d_in[2],
        (const float*)d_in[3], (const float*)d_in[4], (const float*)d_in[5],
        (const float*)d_in[6], (const float*)d_in[7], (const float*)d_in[8],
        (const float*)d_in[9], (const float*)d_in[10],
        (float*)d_out);
}